// Round 2
// baseline (529.910 us; speedup 1.0000x reference)
//
#include <hip/hip_runtime.h>

#define NI 2048   // num_in_caps
#define NJ 64     // num_caps
#define NC 32     // caps_dim
#define NB 32     // batch
#define ND 16     // in_caps_dim

// async global->LDS, 16B per lane, dest = uniform base + lane*16 (HW)
#define GLD_LDS(gsrc, ldst)                                                    \
    __builtin_amdgcn_global_load_lds(                                          \
        (const __attribute__((address_space(1))) unsigned int*)(gsrc),         \
        (__attribute__((address_space(3))) unsigned int*)(ldst), 16, 0, 0)

// ---------------- init (atomic fallback only) ----------------
__global__ void caps_init(float* __restrict__ ws) {
    ws[blockIdx.x * 256 + threadIdx.x] = 0.0f;
}

// ---------------- main ----------------
// grid 512 = 32 j-pairs x 16 i-chunks(128 i). block 256 (4 waves), 2 blocks/CU.
// lane: q = lane&3 (d-quad), cb = (lane>>2)&7, bh = lane>>5 (batch half)
// per lane: acc[2 j][4 c][16 b] = 128 regs; each x float4 feeds 32 FMAs.
// W: register-only rolling prefetch (1 i ahead). x: LDS, 2 x 16-i buffers,
// staged with global_load_lds; one barrier per 16-i phase.
template<int MODE>   // 0 = partial-slab writes, 1 = atomicAdd
__global__ __launch_bounds__(256, 2)
void caps_main(const float* __restrict__ x, const float* __restrict__ W,
               float* __restrict__ ws)
{
    __shared__ float xs[2][8192];   // [buf][il 0..15][b 0..31][d 0..15]

    const int tid  = threadIdx.x;
    const int w    = tid >> 6;
    const int lane = tid & 63;
    const int q    = lane & 3;
    const int cb   = (lane >> 2) & 7;
    const int bh   = lane >> 5;

    const int jp    = blockIdx.x >> 4;
    const int ic    = blockIdx.x & 15;
    const int jbase = jp * 2;
    const int ibase = ic * 128;

    const float4* __restrict__ W4 = (const float4*)W;
    const int cq = cb * 4 + q;   // float4 offset inside W[j][i] for (c=cb, dquad=q)

    float acc[8][16];            // [jj*4+m][boff]
#pragma unroll
    for (int u = 0; u < 8; ++u)
#pragma unroll
        for (int bo = 0; bo < 16; ++bo) acc[u][bo] = 0.0f;

    float4 wb[2][8];

#define LOADW(dst, i_) {                                                      \
        int base_ = ((jbase) * NI + (i_)) * 128 + cq;                         \
        dst[0] = W4[base_];                                                   \
        dst[1] = W4[base_ + 32];                                              \
        dst[2] = W4[base_ + 64];                                              \
        dst[3] = W4[base_ + 96];                                              \
        dst[4] = W4[base_ + NI * 128];                                        \
        dst[5] = W4[base_ + NI * 128 + 32];                                   \
        dst[6] = W4[base_ + NI * 128 + 64];                                   \
        dst[7] = W4[base_ + NI * 128 + 96]; }

#define STAGE(bf_, ph_) {                                                     \
        int ib_ = ibase + (ph_) * 16;                                         \
        _Pragma("unroll")                                                     \
        for (int k = 0; k < 8; ++k) {                                         \
            int il_ = (w << 2) + (k >> 1);                                    \
            int h_  = k & 1;                                                  \
            int bb_ = (h_ << 4) + (lane >> 2);                                \
            const float* src_ = x + (bb_ * NI + ib_ + il_) * 16 + q * 4;      \
            float* dst_ = &xs[bf_][il_ * 512 + h_ * 256];                     \
            GLD_LDS(src_, dst_);                                              \
        } }

    // prologue: W for t=0, x phase 0 into buffer 0
    LOADW(wb[0], ibase + (w << 2));
    STAGE(0, 0)
    __syncthreads();

    int bf = 0;
    for (int p = 0; p < 8; ++p) {
        if (p < 7) STAGE(bf ^ 1, p + 1)
#pragma unroll
        for (int ii = 0; ii < 4; ++ii) {
            int t = (p << 2) + ii;
            if (t < 31) {                       // rolling W prefetch (next i)
                int tn = t + 1;
                int inext = ibase + ((tn >> 2) << 4) + (w << 2) + (tn & 3);
                LOADW(wb[(ii + 1) & 1], inext)
            }
            const int il = (w << 2) + ii;
            const float* xp = &xs[bf][il * 512 + (bh << 8) + (q << 2)];
            const float4* wc = wb[ii & 1];
#pragma unroll
            for (int bo = 0; bo < 16; ++bo) {
                float4 xv = *(const float4*)(xp + bo * 16);
#pragma unroll
                for (int u = 0; u < 8; ++u) {
                    acc[u][bo] = fmaf(wc[u].x, xv.x, acc[u][bo]);
                    acc[u][bo] = fmaf(wc[u].y, xv.y, acc[u][bo]);
                    acc[u][bo] = fmaf(wc[u].z, xv.z, acc[u][bo]);
                    acc[u][bo] = fmaf(wc[u].w, xv.w, acc[u][bo]);
                }
            }
        }
        __syncthreads();
        bf ^= 1;
    }

    // reduce over q (lane bits 0,1): butterfly -> all q-lanes hold d-sum
#pragma unroll
    for (int u = 0; u < 8; ++u)
#pragma unroll
        for (int bo = 0; bo < 16; ++bo) {
            float v = acc[u][bo];
            v += __shfl_xor(v, 1, 64);
            v += __shfl_xor(v, 2, 64);
            acc[u][bo] = v;
        }

    // cross-wave reduce via LDS (reuse xs[0]): red[w][jj][b][c]
    float* red = &xs[0][0];   // 8192 floats
    if (q == 0) {
#pragma unroll
        for (int u = 0; u < 8; ++u) {
            int jj = u >> 2, m = u & 3;
            int c = cb + (m << 3);
#pragma unroll
            for (int bo = 0; bo < 16; ++bo) {
                int b = (bh << 4) + bo;
                red[(w * 2 + jj) * 1024 + b * 32 + c] = acc[u][bo];
            }
        }
    }
    __syncthreads();

#pragma unroll
    for (int r = 0; r < 8; ++r) {
        int oi  = (r << 8) + tid;          // jj*1024 + b*32 + c
        int jj  = oi >> 10;
        int rem = oi & 1023;
        float s = red[jj * 1024 + rem] + red[jj * 1024 + rem + 2048]
                + red[jj * 1024 + rem + 4096] + red[jj * 1024 + rem + 6144];
        int b = rem >> 5, c = rem & 31;
        if (MODE == 0) {
            ws[((ic * NB + b) * NJ + (jbase + jj)) * NC + c] = s;
        } else {
            atomicAdd(&ws[(b * NJ + jbase + jj) * NC + c], s);
        }
    }
#undef LOADW
#undef STAGE
}

// ---------------- finalize: partial-slab path ----------------
__global__ void caps_finalize_p(const float* __restrict__ ws, float* __restrict__ out) {
    int o = blockIdx.x * 256 + threadIdx.x;   // (b*64 + j)*32 + c
    int b = o >> 11;
    int rest = o & 2047;                      // j*32 + c
    float v = 0.0f;
#pragma unroll
    for (int icc = 0; icc < 16; ++icc)
        v += ws[(icc * NB + b) * 2048 + rest];
    v *= (1.0f / 64.0f);
    float sq = v * v;
    sq += __shfl_xor(sq, 1, 64);
    sq += __shfl_xor(sq, 2, 64);
    sq += __shfl_xor(sq, 4, 64);
    sq += __shfl_xor(sq, 8, 64);
    sq += __shfl_xor(sq, 16, 64);
    float scale = sq / (1.0f + sq) / sqrtf(sq + 1e-7f);
    out[o] = scale * v;
}

// ---------------- finalize: atomic path ----------------
__global__ void caps_finalize_a(const float* __restrict__ ws, float* __restrict__ out) {
    int o = blockIdx.x * 256 + threadIdx.x;
    float v = ws[o] * (1.0f / 64.0f);
    float sq = v * v;
    sq += __shfl_xor(sq, 1, 64);
    sq += __shfl_xor(sq, 2, 64);
    sq += __shfl_xor(sq, 4, 64);
    sq += __shfl_xor(sq, 16, 64);
    sq += __shfl_xor(sq, 8, 64);
    float scale = sq / (1.0f + sq) / sqrtf(sq + 1e-7f);
    out[o] = scale * v;
}

extern "C" void kernel_launch(void* const* d_in, const int* in_sizes, int n_in,
                              void* d_out, int out_size, void* d_ws, size_t ws_size,
                              hipStream_t stream) {
    const float* x = (const float*)d_in[0];   // (32, 2048, 16) fp32
    const float* W = (const float*)d_in[1];   // (64, 2048, 32, 16) fp32
    float* out = (float*)d_out;               // (32, 64, 32) fp32

    const size_t slab = (size_t)16 * 65536 * sizeof(float);   // 4 MiB
    if (ws_size >= slab) {
        float* ws = (float*)d_ws;
        hipLaunchKernelGGL(caps_main<0>,     dim3(512), dim3(256), 0, stream, x, W, ws);
        hipLaunchKernelGGL(caps_finalize_p,  dim3(256), dim3(256), 0, stream, ws, out);
    } else {
        float* acc_buf = (ws_size >= (size_t)65536 * sizeof(float)) ? (float*)d_ws : out;
        hipLaunchKernelGGL(caps_init,        dim3(256), dim3(256), 0, stream, acc_buf);
        hipLaunchKernelGGL(caps_main<1>,     dim3(512), dim3(256), 0, stream, x, W, acc_buf);
        hipLaunchKernelGGL(caps_finalize_a,  dim3(256), dim3(256), 0, stream, acc_buf, out);
    }
}

// Round 3
// 138.800 us; speedup vs baseline: 3.8178x; 3.8178x over previous
//
#include <hip/hip_runtime.h>

typedef __attribute__((ext_vector_type(16))) float f16x;

// ---------------- main ----------------
// lane = (j_lo = lane>>5, c = lane&31); each lane owns acc[b=0..31] for its (j,c).
// W: global->VGPR rolling double buffer (named vars, fully static).
// x: wave-uniform s_load_dwordx16 (one per b), 4 b per asm batch, wait bundled.
// No LDS / no barriers in the hot loop; one LDS reduce at the end.
template<int ICHUNK>   // i per block (64 -> 1024 blocks, 128 -> 512 blocks)
__global__ __launch_bounds__(256, 4)
void caps_main(const float* __restrict__ x, const float* __restrict__ W,
               float* __restrict__ ws)
{
    constexpr int NIC = 2048 / ICHUNK;   // # i-chunks
    constexpr int NT  = ICHUNK / 4;      // i per wave

    const int tid  = threadIdx.x;
    const int wu   = __builtin_amdgcn_readfirstlane(tid >> 6);  // wave id (uniform)
    const int lane = tid & 63;
    const int jl   = lane >> 5;
    const int c    = lane & 31;

    const int jp    = blockIdx.x / NIC;   // 0..31 (j-pair)
    const int ic    = blockIdx.x % NIC;
    const int j     = jp * 2 + jl;
    const int ibase = ic * ICHUNK;

    const unsigned long long xb = (unsigned long long)(const void*)x;
    const float4* __restrict__ W4 = (const float4*)W;

    float acc[32];
#pragma unroll
    for (int b = 0; b < 32; ++b) acc[b] = 0.0f;

    const int i0 = ibase + wu;                    // wave takes i = i0 + 4t
    int wi = (j * 2048 + i0) * 128 + c * 4;       // float4 index of W[j][i0][c][0]
    int i  = i0;

    float4 wa0, wa1, wa2, wa3, wb0, wb1, wb2, wb3;
    wa0 = W4[wi]; wa1 = W4[wi + 1]; wa2 = W4[wi + 2]; wa3 = W4[wi + 3];

#define DO_I(i_, q0, q1, q2, q3)                                               \
    {                                                                          \
        float wsv[16];                                                         \
        wsv[0] = q0.x;  wsv[1] = q0.y;  wsv[2] = q0.z;  wsv[3] = q0.w;         \
        wsv[4] = q1.x;  wsv[5] = q1.y;  wsv[6] = q1.z;  wsv[7] = q1.w;         \
        wsv[8] = q2.x;  wsv[9] = q2.y;  wsv[10] = q2.z; wsv[11] = q2.w;        \
        wsv[12] = q3.x; wsv[13] = q3.y; wsv[14] = q3.z; wsv[15] = q3.w;        \
        _Pragma("unroll")                                                      \
        for (int g = 0; g < 8; ++g) {                                          \
            f16x x0, x1, x2, x3;                                               \
            unsigned o0 = (unsigned)((((4 * g + 0) * 2048) + (i_)) * 64);      \
            unsigned o1 = o0 + 2048u * 64u;                                    \
            unsigned o2 = o0 + 2u * 2048u * 64u;                               \
            unsigned o3 = o0 + 3u * 2048u * 64u;                               \
            asm volatile(                                                      \
                "s_load_dwordx16 %0, %4, %5\n\t"                               \
                "s_load_dwordx16 %1, %4, %6\n\t"                               \
                "s_load_dwordx16 %2, %4, %7\n\t"                               \
                "s_load_dwordx16 %3, %4, %8\n\t"                               \
                "s_waitcnt lgkmcnt(0)"                                         \
                : "=&s"(x0), "=&s"(x1), "=&s"(x2), "=&s"(x3)                   \
                : "s"(xb), "s"(o0), "s"(o1), "s"(o2), "s"(o3)                  \
                : "memory");                                                   \
            _Pragma("unroll")                                                  \
            for (int d = 0; d < 16; ++d) {                                     \
                acc[4 * g + 0] = fmaf(x0[d], wsv[d], acc[4 * g + 0]);          \
                acc[4 * g + 1] = fmaf(x1[d], wsv[d], acc[4 * g + 1]);          \
                acc[4 * g + 2] = fmaf(x2[d], wsv[d], acc[4 * g + 2]);          \
                acc[4 * g + 3] = fmaf(x3[d], wsv[d], acc[4 * g + 3]);          \
            }                                                                  \
        }                                                                      \
    }

#pragma unroll 1
    for (int t = 0; t < NT; t += 2) {
        // prefetch W for i+4 (consumed by the odd half below)
        wb0 = W4[wi + 512]; wb1 = W4[wi + 513];
        wb2 = W4[wi + 514]; wb3 = W4[wi + 515];
        DO_I(i, wa0, wa1, wa2, wa3)
        if (t + 2 < NT) {   // prefetch W for i+8 (next even half)
            wa0 = W4[wi + 1024]; wa1 = W4[wi + 1025];
            wa2 = W4[wi + 1026]; wa3 = W4[wi + 1027];
        }
        DO_I(i + 4, wb0, wb1, wb2, wb3)
        wi += 1024; i += 8;
    }
#undef DO_I

    // ---- epilogue: cross-wave reduce (single barrier, outside hot loop) ----
    __shared__ float red[4][2048];
    {
        const int base = jl * 32 + c;
#pragma unroll
        for (int b = 0; b < 32; ++b) red[wu][b * 64 + base] = acc[b];
    }
    __syncthreads();
#pragma unroll
    for (int r = 0; r < 8; ++r) {
        int oi  = r * 256 + tid;          // b*64 + (jl2*32 + c2)
        float s = red[0][oi] + red[1][oi] + red[2][oi] + red[3][oi];
        int b   = oi >> 6;
        int rem = oi & 63;
        // slab layout: [ic][b][j][c]
        ws[(ic * 32 + b) * 2048 + jp * 64 + rem] = s;
    }
}

// ---------------- finalize: sum chunks, scale 1/64, squash over c ----------------
template<int NIC>
__global__ void caps_finalize(const float* __restrict__ ws, float* __restrict__ out) {
    int o = blockIdx.x * 256 + threadIdx.x;   // (b*64 + j)*32 + c ; grid 256
    int b = o >> 11;
    int rest = o & 2047;                      // j*32 + c
    float v = 0.0f;
#pragma unroll
    for (int k = 0; k < NIC; ++k) v += ws[(k * 32 + b) * 2048 + rest];
    v *= (1.0f / 64.0f);
    float sq = v * v;
    sq += __shfl_xor(sq, 1, 64);
    sq += __shfl_xor(sq, 2, 64);
    sq += __shfl_xor(sq, 4, 64);
    sq += __shfl_xor(sq, 8, 64);
    sq += __shfl_xor(sq, 16, 64);
    float scale = sq / (1.0f + sq) / sqrtf(sq + 1e-7f);
    out[o] = scale * v;
}

extern "C" void kernel_launch(void* const* d_in, const int* in_sizes, int n_in,
                              void* d_out, int out_size, void* d_ws, size_t ws_size,
                              hipStream_t stream) {
    const float* x = (const float*)d_in[0];   // (32, 2048, 16) fp32
    const float* W = (const float*)d_in[1];   // (64, 2048, 32, 16) fp32
    float* out = (float*)d_out;               // (32, 64, 32) fp32
    float* ws  = (float*)d_ws;

    if (ws_size >= (size_t)32 * 65536 * sizeof(float)) {        // 8 MiB slab
        hipLaunchKernelGGL((caps_main<64>),  dim3(32 * 32), dim3(256), 0, stream, x, W, ws);
        hipLaunchKernelGGL((caps_finalize<32>), dim3(256),  dim3(256), 0, stream, ws, out);
    } else {                                                    // 4 MiB slab (proven in R2)
        hipLaunchKernelGGL((caps_main<128>), dim3(32 * 16), dim3(256), 0, stream, x, W, ws);
        hipLaunchKernelGGL((caps_finalize<16>), dim3(256),  dim3(256), 0, stream, ws, out);
    }
}

// Round 4
// 59.854 us; speedup vs baseline: 8.8534x; 2.3190x over previous
//
#include <hip/hip_runtime.h>

typedef __attribute__((ext_vector_type(8)))  short bf16x8;
typedef __attribute__((ext_vector_type(16))) float f32x16;
typedef __attribute__((ext_vector_type(4)))  int   i32x4;

// pack 8 fp32 -> 8 bf16 (RNE) in fragment order: reg r holds elems {2r, 2r+1}
__device__ __forceinline__ unsigned cvt2(float lo, float hi) {
    unsigned r;
    asm volatile("v_cvt_pk_bf16_f32 %0, %1, %2" : "=v"(r) : "v"(lo), "v"(hi));
    return r;
}
__device__ __forceinline__ bf16x8 pack8(float4 a, float4 b) {
    union { i32x4 i; bf16x8 h; } c;
    c.i.x = cvt2(a.x, a.y);
    c.i.y = cvt2(a.z, a.w);
    c.i.z = cvt2(b.x, b.y);
    c.i.w = cvt2(b.z, b.w);
    return c.h;
}

// ---------------- init (atomic fallback only) ----------------
__global__ void caps_init(float* __restrict__ ws) {
    ws[blockIdx.x * 256 + threadIdx.x] = 0.0f;   // grid 256
}

// ---------------- main: MFMA bf16 ----------------
// grid 1024 = 64 j * 16 ic (128 i each), block 256 = 4 waves, 4 blocks/CU.
// wave w handles i = ibase + w + 4t, t = 0..31. One v_mfma_f32_32x32x16_bf16
// per i: A = x[32 b][16 d], B = W[j,i][16 d][32 c].
// A-frag: lane l reads x[b=l&31][i][d=(l>>5)*8 ..+7]   (32B fp32, L2-resident gather)
// B-frag: lane l reads W[j][i][c=l&31][d=(l>>5)*8 ..+7] (32B fp32, coalesced 2KB/wave)
// No LDS / barriers in hot loop. Cross-wave C reduce once at the end.
template<int MODE>   // 0 = slab partials, 1 = atomicAdd
__global__ __launch_bounds__(256, 4)
void caps_mfma(const float* __restrict__ x, const float* __restrict__ W,
               float* __restrict__ ws)
{
    const int tid  = threadIdx.x;
    const int w    = tid >> 6;
    const int lane = tid & 63;
    const int m    = lane & 31;   // b for A / c for B
    const int h    = lane >> 5;   // k-half

    const int j     = blockIdx.x >> 4;
    const int ic    = blockIdx.x & 15;
    const int ibase = ic * 128;

    // byte addresses for i = ibase + w
    const char* Wb = (const char*)W + (((size_t)(j * 2048 + ibase + w)) << 11)
                   + (m << 6) + (h << 5);
    const char* Xb = (const char*)x + ((size_t)m << 17) + ((ibase + w) << 6) + (h << 5);

    f32x16 acc = {};

    float4 wA0 = *(const float4*)(Wb);
    float4 wA1 = *(const float4*)(Wb + 16);
    float4 xA0 = *(const float4*)(Xb);
    float4 xA1 = *(const float4*)(Xb + 16);

#pragma unroll 1
    for (int t = 0; t < 32; t += 2) {
        // prefetch odd half (i + 4): W step = 4*2048B, x step = 4*64B
        float4 wB0 = *(const float4*)(Wb + 8192);
        float4 wB1 = *(const float4*)(Wb + 8192 + 16);
        float4 xB0 = *(const float4*)(Xb + 256);
        float4 xB1 = *(const float4*)(Xb + 256 + 16);

        acc = __builtin_amdgcn_mfma_f32_32x32x16_bf16(
                  pack8(xA0, xA1), pack8(wA0, wA1), acc, 0, 0, 0);

        if (t + 2 < 32) {   // prefetch next even half (i + 8)
            wA0 = *(const float4*)(Wb + 16384);
            wA1 = *(const float4*)(Wb + 16384 + 16);
            xA0 = *(const float4*)(Xb + 512);
            xA1 = *(const float4*)(Xb + 512 + 16);
        }

        acc = __builtin_amdgcn_mfma_f32_32x32x16_bf16(
                  pack8(xB0, xB1), pack8(wB0, wB1), acc, 0, 0, 0);

        Wb += 16384; Xb += 512;
    }

    // ---- cross-wave reduce of C (b = (r&3)+8*(r>>2)+4*(lane>>5), c = lane&31) ----
    __shared__ float red[4096];   // [w][reg 0..15][lane 0..63]
#pragma unroll
    for (int r = 0; r < 16; ++r)
        red[w * 1024 + r * 64 + lane] = acc[r];
    __syncthreads();

#pragma unroll
    for (int e = 0; e < 4; ++e) {
        int idx = e * 256 + tid;             // b*32 + c
        int b = idx >> 5, c = idx & 31;
        int l = (((b >> 2) & 1) << 5) + c;
        int r = (b & 3) | (((b >> 3) & 3) << 2);
        float s = red[r * 64 + l] + red[1024 + r * 64 + l]
                + red[2048 + r * 64 + l] + red[3072 + r * 64 + l];
        if (MODE == 0)
            ws[(ic * 32 + b) * 2048 + j * 32 + c] = s;   // slab [ic][b][j*32+c]
        else
            atomicAdd(&ws[b * 2048 + j * 32 + c], s);
    }
}

// ---------------- finalize: sum chunks, scale 1/64, squash over c ----------------
template<int NIC>
__global__ void caps_finalize(const float* __restrict__ ws, float* __restrict__ out) {
    int o = blockIdx.x * 256 + threadIdx.x;   // b*2048 + j*32 + c ; grid 256
    int b = o >> 11;
    int rest = o & 2047;
    float v = 0.0f;
#pragma unroll
    for (int k = 0; k < NIC; ++k) v += ws[(k * 32 + b) * 2048 + rest];
    v *= (1.0f / 64.0f);
    float sq = v * v;
    sq += __shfl_xor(sq, 1, 64);
    sq += __shfl_xor(sq, 2, 64);
    sq += __shfl_xor(sq, 4, 64);
    sq += __shfl_xor(sq, 8, 64);
    sq += __shfl_xor(sq, 16, 64);
    float scale = sq / (1.0f + sq) / sqrtf(sq + 1e-7f);
    out[o] = scale * v;
}

// atomic-path finalize (ws already fully reduced)
__global__ void caps_finalize_a(const float* __restrict__ ws, float* __restrict__ out) {
    int o = blockIdx.x * 256 + threadIdx.x;
    float v = ws[o] * (1.0f / 64.0f);
    float sq = v * v;
    sq += __shfl_xor(sq, 1, 64);
    sq += __shfl_xor(sq, 2, 64);
    sq += __shfl_xor(sq, 4, 64);
    sq += __shfl_xor(sq, 8, 64);
    sq += __shfl_xor(sq, 16, 64);
    float scale = sq / (1.0f + sq) / sqrtf(sq + 1e-7f);
    out[o] = scale * v;
}

extern "C" void kernel_launch(void* const* d_in, const int* in_sizes, int n_in,
                              void* d_out, int out_size, void* d_ws, size_t ws_size,
                              hipStream_t stream) {
    (void)in_sizes; (void)n_in; (void)out_size;
    const float* x = (const float*)d_in[0];   // (32, 2048, 16) fp32
    const float* W = (const float*)d_in[1];   // (64, 2048, 32, 16) fp32
    float* out = (float*)d_out;               // (32, 64, 32) fp32
    float* ws  = (float*)d_ws;

    if (ws_size >= (size_t)16 * 65536 * sizeof(float)) {      // 4 MiB slab (proven)
        hipLaunchKernelGGL((caps_mfma<0>),     dim3(1024), dim3(256), 0, stream, x, W, ws);
        hipLaunchKernelGGL((caps_finalize<16>),dim3(256),  dim3(256), 0, stream, ws, out);
    } else {                                                  // atomic fallback
        float* acc_buf = (ws_size >= (size_t)65536 * sizeof(float)) ? ws : out;
        hipLaunchKernelGGL(caps_init,          dim3(256),  dim3(256), 0, stream, acc_buf);
        hipLaunchKernelGGL((caps_mfma<1>),     dim3(1024), dim3(256), 0, stream, x, W, acc_buf);
        hipLaunchKernelGGL(caps_finalize_a,    dim3(256),  dim3(256), 0, stream, acc_buf, out);
    }
}